// Round 4
// baseline (241.283 us; speedup 1.0000x reference)
//
#include <hip/hip_runtime.h>
#include <stdint.h>

#define NNODES 10000
#define NEDGES 100000
#define DNODE 56
#define JTOT 1600
#define HBLK 391   // k_hidden blocks
#define TBLK 400   // k_tr blocks

typedef __attribute__((ext_vector_type(8))) short short8;
typedef __attribute__((ext_vector_type(4))) float floatx4;

__device__ __forceinline__ unsigned short f2bf(float f) {
  unsigned u = __float_as_uint(f);
  u = u + 0x7fffu + ((u >> 16) & 1u);
  return (unsigned short)(u >> 16);
}

__device__ __forceinline__ float mishf(float x) {
  float e = __expf(x);
  float z = 1.f + e; z = z * z;
  float t = (z - 1.f) / (z + 1.f);
  t = (x > 40.f) ? 1.f : t;
  return x * t;
}

// ---- fused: blocks [0,391) h = mish(ea@fc1+b1) + src histogram; [391,791) G = bf16(fc2w^T)
__global__ __launch_bounds__(256) void k_hidtr(const float* __restrict__ ea,
                                               const float* __restrict__ fc1w,
                                               const float* __restrict__ fc1b,
                                               const float* __restrict__ fc2w,
                                               const int* __restrict__ eidx,
                                               int* __restrict__ cntn,
                                               unsigned short* __restrict__ hb,
                                               unsigned short* __restrict__ G) {
  int bid = blockIdx.x;
  if (bid >= HBLK) {          // transpose+cast part
    int idx = (bid - HBLK) * 256 + threadIdx.x;
    if (idx < 64 * JTOT) {
      int j = idx >> 6, k = idx & 63;
      G[idx] = f2bf(fc2w[k * JTOT + j]);
    }
    return;
  }
  int e = bid * 256 + threadIdx.x;
  if (e >= NEDGES) return;
  atomicAdd(&cntn[eidx[e]], 1);
  float a[64];
  const float4* row = (const float4*)(ea + (size_t)e * 64);
  #pragma unroll
  for (int i = 0; i < 16; i++) {
    float4 t = row[i];
    a[4*i] = t.x; a[4*i+1] = t.y; a[4*i+2] = t.z; a[4*i+3] = t.w;
  }
  for (int jb = 0; jb < 64; jb += 8) {
    float acc[8];
    #pragma unroll
    for (int i = 0; i < 8; i++) acc[i] = fc1b[jb + i];
    #pragma unroll
    for (int k = 0; k < 64; k++) {
      #pragma unroll
      for (int i = 0; i < 8; i++) acc[i] = fmaf(a[k], fc1w[k*64 + jb + i], acc[i]);
    }
    unsigned pk[4];
    #pragma unroll
    for (int i = 0; i < 4; i++) {
      unsigned lo = f2bf(mishf(acc[2*i]));
      unsigned hi = f2bf(mishf(acc[2*i+1]));
      pk[i] = lo | (hi << 16);
    }
    *(uint4*)(hb + (size_t)e*64 + jb) = make_uint4(pk[0], pk[1], pk[2], pk[3]);
  }
}

__global__ __launch_bounds__(1024) void k_scan(const int* __restrict__ cntn,
                                               int* __restrict__ offs,
                                               int* __restrict__ cursor) {
  __shared__ int ts[1024];
  int t = threadIdx.x;
  int base = t * 10;
  int loc[10]; int s = 0;
  #pragma unroll
  for (int i = 0; i < 10; i++) {
    int idx = base + i;
    int v = (idx < NNODES) ? cntn[idx] : 0;
    loc[i] = s; s += v;
  }
  ts[t] = s;
  __syncthreads();
  for (int off = 1; off < 1024; off <<= 1) {
    int v = (t >= off) ? ts[t - off] : 0;
    __syncthreads();
    ts[t] += v;
    __syncthreads();
  }
  int excl = (t == 0) ? 0 : ts[t - 1];
  #pragma unroll
  for (int i = 0; i < 10; i++) {
    int idx = base + i;
    if (idx < NNODES) { int o = excl + loc[i]; offs[idx] = o; cursor[idx] = o; }
  }
  if (t == 1023) offs[NNODES] = ts[1023];
}

// ---- fused GEMM2 + tensor product. Block = 4 waves; wave = 32 edges (nt=2).
// G tiles (16 j-rows x 64 k, 2KB) staged into LDS double-buffered, XOR-swizzled.
__global__ __launch_bounds__(256, 3) void k_tp(
    const unsigned short* __restrict__ hb,
    const unsigned short* __restrict__ G,
    const float* __restrict__ fc2b,
    const int* __restrict__ eidx,
    const float* __restrict__ node_attr,
    const float* __restrict__ edge_sh,
    int* __restrict__ cursor,
    float* __restrict__ tp) {
  __shared__ short Gs[2][2][1024];     // [buf][tile parity][16 rows x 64 k]
  __shared__ float b2s[JTOT];
  __shared__ float Wt4[4][64 * 32];    // per-wave coef table: row u x 32 edges
  __shared__ int pos_s[4][32];
  const int tid = threadIdx.x;
  const int wave = tid >> 6, lane = tid & 63;
  for (int i = tid; i < JTOT; i += 256) b2s[i] = fc2b[i];

  const int e0w = blockIdx.x * 128 + wave * 32;
  float* Wt = &Wt4[wave][0];
  {
    int el = lane & 31, hh = lane >> 5;
    int e = e0w + el;
    bool valid = e < NEDGES;
    int dst = valid ? eidx[NEDGES + e] : 0;
    const float* na = node_attr + (size_t)dst * DNODE;
    if (hh == 0) {
      pos_s[wave][el] = valid ? atomicAdd(&cursor[eidx[e]], 1) : 0;
      #pragma unroll
      for (int u = 0; u < 32; u += 4) {
        float4 t = valid ? *(const float4*)(na + u) : make_float4(0.f,0.f,0.f,0.f);
        Wt[(u+0)*32 + el] = t.x;
        Wt[(u+1)*32 + el] = t.y;
        Wt[(u+2)*32 + el] = t.z;
        Wt[(u+3)*32 + el] = t.w;
      }
    } else {
      float4 sh = valid ? *(const float4*)(edge_sh + 4*(size_t)e) : make_float4(0.f,0.f,0.f,0.f);
      const float rs3 = 0.57735026918962576f;
      #pragma unroll
      for (int u = 0; u < 8; u++) {
        float v0 = valid ? na[32 + u*3 + 0] : 0.f;
        float v1 = valid ? na[32 + u*3 + 1] : 0.f;
        float v2 = valid ? na[32 + u*3 + 2] : 0.f;
        Wt[(32 + u*3 + 0)*32 + el] = v0;
        Wt[(32 + u*3 + 1)*32 + el] = v1;
        Wt[(32 + u*3 + 2)*32 + el] = v2;
        Wt[(56 + u)*32 + el] = (v0*sh.y + v1*sh.z + v2*sh.w) * rs3;
      }
    }
  }

  const int col = lane & 15, rg = lane >> 4, rgh = rg >> 1;
  float sh0c[2], sh1c[2][3];
  bool vld[2];
  short8 bfrag[2][2];
  const short8 zfrag = {0,0,0,0,0,0,0,0};
  #pragma unroll
  for (int nt = 0; nt < 2; nt++) {
    int e = e0w + nt*16 + col;
    bool v = e < NEDGES; vld[nt] = v;
    if (v) {
      float4 sh = *(const float4*)(edge_sh + 4*(size_t)e);
      sh0c[nt] = sh.x; sh1c[nt][0] = sh.y; sh1c[nt][1] = sh.z; sh1c[nt][2] = sh.w;
      const unsigned short* hp = hb + (size_t)e * 64;
      bfrag[nt][0] = *(const short8*)(hp + rg*8);
      bfrag[nt][1] = *(const short8*)(hp + 32 + rg*8);
    } else {
      sh0c[nt] = 0.f; sh1c[nt][0] = sh1c[nt][1] = sh1c[nt][2] = 0.f;
      bfrag[nt][0] = zfrag; bfrag[nt][1] = zfrag;
    }
  }

  float sacc[2][8], vacc[2][12];
  #pragma unroll
  for (int nt = 0; nt < 2; nt++) {
    #pragma unroll
    for (int i = 0; i < 8; i++) sacc[nt][i] = 0.f;
    #pragma unroll
    for (int i = 0; i < 12; i++) vacc[nt][i] = 0.f;
  }

  // stage chunk c (tiles 2c, 2c+1) into Gs[c&1]; 256 thr x 1 granule(16B)
  auto stage = [&](int c) {
    int t = tid >> 7, gt = tid & 127;          // tile parity, granule in tile
    int jp = gt >> 3, g = gt & 7;
    int gsw = (gt & ~7) | (g ^ (jp & 7));      // xor-swizzle within row block
    short8 v = *(const short8*)(G + (size_t)c*2048 + tid*8);
    *(short8*)(&Gs[c&1][t][gsw*8]) = v;
  };

  const int g0 = (rg ^ (col & 7)) * 8;         // frag0 granule offset (swizzled)
  const int g1 = ((rg + 4) ^ (col & 7)) * 8;

  stage(0);
  __syncthreads();

  #pragma unroll 1
  for (int c = 0; c < 50; c++) {
    if (c < 49) stage(c + 1);
    #pragma unroll
    for (int t = 0; t < 2; t++) {
      const int jt = c*2 + t;
      const short* gb = &Gs[c&1][t][0];
      short8 x0 = *(const short8*)(gb + col*64 + g0);
      short8 x1 = *(const short8*)(gb + col*64 + g1);
      float4 bb = *(const float4*)&b2s[jt*16 + rg*4];
      floatx4 acc[2];
      #pragma unroll
      for (int nt = 0; nt < 2; nt++) {
        floatx4 cc = {bb.x, bb.y, bb.z, bb.w};
        cc = __builtin_amdgcn_mfma_f32_16x16x32_bf16(x0, bfrag[nt][0], cc, 0, 0, 0);
        cc = __builtin_amdgcn_mfma_f32_16x16x32_bf16(x1, bfrag[nt][1], cc, 0, 0, 0);
        acc[nt] = cc;
      }
      if (jt < 64) {                   // w1: u = jt>>1, wi = (jt&1)*16+rg*4+r
        const int u = jt >> 1, p = jt & 1;
        #pragma unroll
        for (int nt = 0; nt < 2; nt++) {
          float cf = Wt[u*32 + nt*16 + col] * sh0c[nt];
          #pragma unroll
          for (int r = 0; r < 4; r++)
            sacc[nt][p*4+r] = fmaf(cf, acc[nt][r], sacc[nt][p*4+r]);
        }
      } else if (jt < 68) {            // w2: u = (jt-64)*2+rgh
        const int u = (jt - 64)*2 + rgh;
        #pragma unroll
        for (int nt = 0; nt < 2; nt++) {
          #pragma unroll
          for (int c3 = 0; c3 < 3; c3++) {
            float cf = Wt[(32 + u*3 + c3)*32 + nt*16 + col] * sh0c[nt];
            #pragma unroll
            for (int r = 0; r < 4; r++)
              vacc[nt][c3*4+r] = fmaf(cf, acc[nt][r], vacc[nt][c3*4+r]);
          }
        }
      } else if (jt < 84) {            // w3: u = (jt-68)*2+rgh
        const int u = (jt - 68)*2 + rgh;
        #pragma unroll
        for (int nt = 0; nt < 2; nt++) {
          float sv = Wt[u*32 + nt*16 + col];
          #pragma unroll
          for (int c3 = 0; c3 < 3; c3++) {
            float cf = sv * sh1c[nt][c3];
            #pragma unroll
            for (int r = 0; r < 4; r++)
              vacc[nt][c3*4+r] = fmaf(cf, acc[nt][r], vacc[nt][c3*4+r]);
          }
        }
      } else {                         // w4: u = (jt-84)>>1
        const int u = (jt - 84) >> 1, p = jt & 1;
        #pragma unroll
        for (int nt = 0; nt < 2; nt++) {
          float cf = Wt[(56 + u)*32 + nt*16 + col];
          #pragma unroll
          for (int r = 0; r < 4; r++)
            sacc[nt][p*4+r] = fmaf(cf, acc[nt][r], sacc[nt][p*4+r]);
        }
      }
    }
    __syncthreads();
  }

  // ---- epilogue: direct stores (scalar 2x16B, vector 3x16B after xor-32 reduce)
  const float ascale = 0.15811388300841897f;   // 1/sqrt(40)
  #pragma unroll
  for (int nt = 0; nt < 2; nt++) {
    int el = nt*16 + col;
    float* rowp = tp + (size_t)pos_s[wave][el] * DNODE;
    if (vld[nt]) {
      #pragma unroll
      for (int p = 0; p < 2; p++) {
        float4 v = make_float4(ascale*sacc[nt][p*4+0], ascale*sacc[nt][p*4+1],
                               ascale*sacc[nt][p*4+2], ascale*sacc[nt][p*4+3]);
        *(float4*)(rowp + p*16 + rg*4) = v;
      }
    }
    float vtot[12];
    #pragma unroll
    for (int k = 0; k < 12; k++)
      vtot[k] = (vacc[nt][k] + __shfl_xor(vacc[nt][k], 32)) * ascale;
    if (rg < 2 && vld[nt]) {
      float tmp[12];
      #pragma unroll
      for (int c3 = 0; c3 < 3; c3++)
        #pragma unroll
        for (int r = 0; r < 4; r++) tmp[r*3 + c3] = vtot[c3*4 + r];
      #pragma unroll
      for (int j = 0; j < 3; j++)
        *(float4*)(rowp + 32 + (rg & 1)*12 + j*4) = *(float4*)&tmp[j*4];
    }
  }
}

// ---- per-node mean + residual + BN partials (contiguous CSR rows)
__global__ __launch_bounds__(256) void k_gather(const float* __restrict__ tp,
                                                const int* __restrict__ offs,
                                                const float* __restrict__ node_attr,
                                                float* __restrict__ pre,
                                                float* __restrict__ pstat) {
  __shared__ float redS[4*64], redQ[4*64];
  int t = threadIdx.x, wave = t >> 6, lane = t & 63;
  int gw = blockIdx.x * 4 + wave;
  const int W = 640 * 4;
  int off = (lane < DNODE) ? lane : 0;
  float ssum = 0.f, ssq = 0.f;
  for (int n = gw; n < NNODES; n += W) {
    int beg = offs[n], end = offs[n+1];
    float acc = 0.f;
    int i = beg;
    for (; i + 4 <= end; i += 4) {
      float v0 = tp[(size_t)(i+0)*DNODE + off];
      float v1 = tp[(size_t)(i+1)*DNODE + off];
      float v2 = tp[(size_t)(i+2)*DNODE + off];
      float v3 = tp[(size_t)(i+3)*DNODE + off];
      acc += (v0 + v1) + (v2 + v3);
    }
    for (; i < end; i++) acc += tp[(size_t)i*DNODE + off];
    int c = end - beg; if (c < 1) c = 1;
    float m = acc / (float)c + node_attr[(size_t)n*DNODE + off];
    if (lane < DNODE) { pre[(size_t)n*DNODE + lane] = m; ssum += m; ssq += m*m; }
  }
  redS[wave*64 + lane] = ssum;
  redQ[wave*64 + lane] = ssq;
  __syncthreads();
  if (wave == 0 && lane < DNODE) {
    float a = redS[lane] + redS[64+lane] + redS[128+lane] + redS[192+lane];
    float b = redQ[lane] + redQ[64+lane] + redQ[128+lane] + redQ[192+lane];
    pstat[(size_t)blockIdx.x*112 + lane] = a;
    pstat[(size_t)blockIdx.x*112 + 56 + lane] = b;
  }
}

__global__ __launch_bounds__(256) void k_stats(const float* __restrict__ pstat,
                                               float* __restrict__ stats) {
  int f = blockIdx.x * 4 + (threadIdx.x >> 6);
  int lane = threadIdx.x & 63;
  float v = 0.f;
  for (int b = lane; b < 640; b += 64) v += pstat[(size_t)b*112 + f];
  #pragma unroll
  for (int o = 32; o; o >>= 1) v += __shfl_xor(v, o);
  if (lane == 0) stats[f] = v;
}

__global__ __launch_bounds__(256) void k_norm(const float* __restrict__ pre,
                                              const float* __restrict__ stats,
                                              const float* __restrict__ gs,
                                              const float* __restrict__ bs,
                                              const float* __restrict__ gv,
                                              float* __restrict__ out) {
  int idx = blockIdx.x * 256 + threadIdx.x;
  if (idx >= NNODES * DNODE) return;
  int n = idx / DNODE;
  int d = idx - n * DNODE;
  float val = pre[idx];
  const float invN = 1.f / (float)NNODES;
  float res;
  if (d < 32) {
    float mu = stats[d] * invN;
    float var = stats[56 + d] * invN - mu * mu;
    res = (val - mu) * rsqrtf(var + 1e-4f) * gs[d] + bs[d];
  } else {
    int wi = (d - 32) / 3;
    float vn = (stats[56 + 32 + wi*3] + stats[56 + 32 + wi*3 + 1] +
                stats[56 + 32 + wi*3 + 2]) * (invN / 3.f);
    res = val * rsqrtf(vn + 1e-4f) * gv[wi];
  }
  out[idx] = res;
}

extern "C" void kernel_launch(void* const* d_in, const int* in_sizes, int n_in,
                              void* d_out, int out_size, void* d_ws, size_t ws_size,
                              hipStream_t stream) {
  const float* node_attr = (const float*)d_in[0];
  const int*   eidx      = (const int*)d_in[1];
  const float* edge_attr = (const float*)d_in[2];
  const float* edge_sh   = (const float*)d_in[3];
  const float* fc1w      = (const float*)d_in[4];
  const float* fc1b      = (const float*)d_in[5];
  const float* fc2w      = (const float*)d_in[6];
  const float* fc2b      = (const float*)d_in[7];
  const float* gs        = (const float*)d_in[8];
  const float* bs        = (const float*)d_in[9];
  const float* gv        = (const float*)d_in[10];

  float* ws = (float*)d_ws;
  float* tp    = ws;                                    // 5,600,000
  float* pre   = ws + 5600000;                          // 560,000
  float* stats = ws + 6160000;                          // 112 (pad 128)
  float* pstat = ws + 6160128;                          // 71,680
  int*   cntn  = (int*)(ws + 6231808);                  // 10,000
  int*   offs  = (int*)(ws + 6241808);                  // 10,001 (pad 10,008)
  int*   cursor= (int*)(ws + 6251816);                  // 10,000
  unsigned short* G  = (unsigned short*)(ws + 6261816); // 102,400 shorts (51,200 f)
  unsigned short* hb = (unsigned short*)(ws + 6313016); // 6,400,000 shorts
  // end = 9,513,016 floats = 38.1 MB

  hipMemsetAsync(cntn, 0, (size_t)10000 * 4, stream);
  k_hidtr<<<HBLK + TBLK, 256, 0, stream>>>(edge_attr, fc1w, fc1b, fc2w, eidx, cntn, hb, G);
  k_scan<<<1, 1024, 0, stream>>>(cntn, offs, cursor);
  k_tp<<<782, 256, 0, stream>>>(hb, G, fc2b, eidx, node_attr, edge_sh, cursor, tp);
  k_gather<<<640, 256, 0, stream>>>(tp, offs, node_attr, pre, pstat);
  k_stats<<<28, 256, 0, stream>>>(pstat, stats);
  k_norm<<<(NNODES * DNODE + 255) / 256, 256, 0, stream>>>(pre, stats, gs, bs, gv, (float*)d_out);
}